// Round 5
// baseline (1179.094 us; speedup 1.0000x reference)
//
#include <hip/hip_runtime.h>
#include <math.h>

#define TT 2048
#define UU 64
#define BB 256
#define NTHR 320   // 5 waves: 4 producers (one gate each) + 1 layer-1 consumer

typedef float v2f __attribute__((ext_vector_type(2)));
typedef float v4f __attribute__((ext_vector_type(4)));

// Fast activations on v_exp_f32 / v_rcp_f32 (~1e-7 abs err; threshold 3.45e-6;
// validated at absmax 9.5e-7 in rounds 0-4).
__device__ __forceinline__ float frcp(float x) { return __builtin_amdgcn_rcpf(x); }
__device__ __forceinline__ float fsigmoid(float x) { return frcp(1.0f + __expf(-x)); }
__device__ __forceinline__ float ftanh(float x) { return 1.0f - 2.0f * frcp(1.0f + __expf(2.0f * x)); }

// Packed dual-FMA: a.{x,y} += h.{x,y} * w.{x,y}  (one VOP3P instruction).
__device__ __forceinline__ void pkfma(v2f& a, v2f h, v2f w) {
    asm("v_pk_fma_f32 %0, %1, %2, %0" : "+v"(a) : "v"(h), "v"(w));
}

// ROUNDS 0-4 POST-MORTEM: a 168-reg/lane working set (2-wave split) loses to
// the RA every time -- r4's waves_per_eu(1,1) got VGPR 132 and the RA covers
// the shortfall with hidden AGPR copies / remat (no scratch writes, dur stuck).
// FIX: shrink the requirement below the budget instead of raising the budget:
// 4 producer waves, ONE GATE each -> 32 named v2f = 64 weight VGPRs + ~30
// working ~= 95/lane, under even the default 128 budget (waves_per_eu(1,2)
// grants 256+). Keep every r3/r4 win: LDS h-ring broadcast (no readlane
// hazards), v_pk_fma matvec, one barrier/step, overlapped lagged consumer.
//
// Wave g in 0..3: lane u owns W0 column c = g*64+u (gate g of unit u),
//   weights W[k][c], k=0..63 as 32 v2f pairs. Matvec: 16 uniform
//   ds_read_b128 of h[4m..4m+3] from the wave's PRIVATE ring slot + 32
//   v_pk_fma_f32 in 4 chains x 8. z_c -> zbuf[c] (b32), ONE barrier, read 4
//   z's (2x ds_read2_b32), redundant (c0,h) update -- bit-identical in all 4
//   waves -- write own ring slot h[u] (b32). No splats needed: one gate/lane
//   consumes consecutive-k h pairs directly.
// Wave 4 (consumer): after barrier t processes step t-1 from wave0's ring
//   (slot written between B(t) and B(t+1), read after B(t+1), overwritten
//   after B(t+2) -- race-free, proven protocol). 4-value 64-lane shuffle
//   reduce + layer-1 LSTM + dense, banks output, coalesced flush per 64.
// All 5 waves execute exactly 1 + TT + 1 barriers.
__global__
__attribute__((amdgpu_flat_work_group_size(NTHR, NTHR)))
__attribute__((amdgpu_waves_per_eu(1, 2)))
void lstm_ts_kernel(
    const float* __restrict__ x, const float* __restrict__ W0,
    const float* __restrict__ b0, const float* __restrict__ W1,
    const float* __restrict__ b1, const float* __restrict__ Wd,
    const float* __restrict__ bd, float* __restrict__ out)
{
    __shared__ __align__(16) float xbuf[TT];
    __shared__ __align__(16) float ringP[4][2][UU];  // per-producer private h rings
    __shared__ __align__(16) float zbuf[4 * UU];     // z by gate: [g*64 + u]
    __shared__ float red[5];

    const int tid = threadIdx.x;
    const int wid = tid >> 6;
    const int u = tid & 63;
    const int b = blockIdx.x;
    const float* xrow = x + b * TT;
    float* outrow = out + b * TT;

    // ---- prologue: stage x, sum of squares over T (all 5 waves) ----
    float ss = 0.f;
    for (int i = tid; i < TT; i += NTHR) {
        float v = xrow[i];
        xbuf[i] = v;
        ss += v * v;
    }
    #pragma unroll
    for (int m = 1; m < 64; m <<= 1) ss += __shfl_xor(ss, m, 64);
    if (u == 0) red[wid] = ss;
    if (wid < 4) ringP[wid][1][u] = 0.f;  // h_{-1}=0: step 0 reads slot 1
    __syncthreads();  // B0

    if (wid < 4) {
        // ================= PRODUCER wave: gate g = wid =================
        const int g = wid;
        const int c = g * 64 + u;  // owned W0 column
        const float sq = ((red[0] + red[1]) + (red[2] + red[3])) + red[4];
        const float scale = 1.0f / sqrtf(fmaxf(sq, 1e-12f));  // precise, once

        // 32 named v2f = 64 weight VGPRs; named scalars SROA, pin blocks remat.
        // WP m = (W[2m][c], W[2m+1][c]).
        #define DECLW(m) v2f WP##m; { const float* r_ = W0 + (1 + 2*(m)) * 256 + c; \
            WP##m.x = r_[0]; WP##m.y = r_[256]; } \
            asm volatile("" : "+v"(WP##m));
        DECLW(0)  DECLW(1)  DECLW(2)  DECLW(3)  DECLW(4)  DECLW(5)  DECLW(6)  DECLW(7)
        DECLW(8)  DECLW(9)  DECLW(10) DECLW(11) DECLW(12) DECLW(13) DECLW(14) DECLW(15)
        DECLW(16) DECLW(17) DECLW(18) DECLW(19) DECLW(20) DECLW(21) DECLW(22) DECLW(23)
        DECLW(24) DECLW(25) DECLW(26) DECLW(27) DECLW(28) DECLW(29) DECLW(30) DECLW(31)
        #undef DECLW

        const float wx = W0[c] * scale;  // l2-norm scale folded into x-weight
        const float bc = b0[c];

        float (*myring)[UU] = ringP[g];
        float c0 = 0.f;

        for (int t = 0; t < TT; ++t) {
            const float xr = xbuf[t];                 // uniform broadcast read
            const float* hs = myring[(t + 1) & 1];    // h_{t-1} (own private copy)

            // 4 chains x 8 pk_fma; x-term + bias folded into chain 0
            v2f a0, a1 = 0.f, a2 = 0.f, a3 = 0.f;
            a0.x = fmaf(xr, wx, bc); a0.y = 0.f;

            // one uniform b128 read = (h4m, h4m+1, h4m+2, h4m+3) -> 2 pk_fma
            #define MAC4(m, WA, WB, A, B) { \
                v4f hv_ = *(const v4f*)(hs + 4 * (m)); \
                v2f hA_ = __builtin_shufflevector(hv_, hv_, 0, 1); \
                v2f hB_ = __builtin_shufflevector(hv_, hv_, 2, 3); \
                pkfma(A, hA_, WA); pkfma(B, hB_, WB); \
            }
            MAC4(0,  WP0,  WP1,  a0, a1) MAC4(1,  WP2,  WP3,  a2, a3)
            MAC4(2,  WP4,  WP5,  a0, a1) MAC4(3,  WP6,  WP7,  a2, a3)
            MAC4(4,  WP8,  WP9,  a0, a1) MAC4(5,  WP10, WP11, a2, a3)
            MAC4(6,  WP12, WP13, a0, a1) MAC4(7,  WP14, WP15, a2, a3)
            MAC4(8,  WP16, WP17, a0, a1) MAC4(9,  WP18, WP19, a2, a3)
            MAC4(10, WP20, WP21, a0, a1) MAC4(11, WP22, WP23, a2, a3)
            MAC4(12, WP24, WP25, a0, a1) MAC4(13, WP26, WP27, a2, a3)
            MAC4(14, WP28, WP29, a0, a1) MAC4(15, WP30, WP31, a2, a3)
            #undef MAC4

            const v2f sz = (a0 + a1) + (a2 + a3);
            zbuf[c] = sz.x + sz.y;  // ds_write_b32
            __syncthreads();        // B(t+1): all four gates exchanged

            // redundant unit update -- bit-identical in all 4 producer waves
            const float zi = zbuf[u];
            const float zj = zbuf[64 + u];
            const float zf = zbuf[128 + u];
            const float zo = zbuf[192 + u];
            c0 = fsigmoid(zf + 1.0f) * c0 + fsigmoid(zi) * ftanh(zj);
            const float h = fsigmoid(zo) * ftanh(c0);

            myring[t & 1][u] = h;   // publish h_t (b32, own private ring)
        }
        __syncthreads();  // B(TT+1)
    } else {
        // ================= CONSUMER: layer 1 + dense + store =================
        const float w1v0 = W1[u * 4 + 0], w1v1 = W1[u * 4 + 1];
        const float w1v2 = W1[u * 4 + 2], w1v3 = W1[u * 4 + 3];
        const float w1h0 = W1[256], w1h1 = W1[257], w1h2 = W1[258], w1h3 = W1[259];
        const float b10 = b1[0], b11 = b1[1], b12 = b1[2], b13 = b1[3];
        const float wd = Wd[0], bdv = bd[0];

        float c1 = 0.f, h1 = 0.f, oval = 0.f;

        // reads wave0's ring one step lagged: slot (s)&1 written before
        // barrier s+1, read after it, overwritten only after barrier s+2.
        #define L1STEP(s) { \
            const float hu = ringP[0][(s) & 1][u];  /* 4B stride: conflict-free */ \
            float p0 = hu * w1v0, p1 = hu * w1v1, p2 = hu * w1v2, p3 = hu * w1v3; \
            _Pragma("unroll") \
            for (int m = 1; m < 64; m <<= 1) { \
                p0 += __shfl_xor(p0, m, 64); \
                p1 += __shfl_xor(p1, m, 64); \
                p2 += __shfl_xor(p2, m, 64); \
                p3 += __shfl_xor(p3, m, 64); \
            } \
            const float z1i = p0 + fmaf(h1, w1h0, b10); \
            const float z1j = p1 + fmaf(h1, w1h1, b11); \
            const float z1f = p2 + fmaf(h1, w1h2, b12); \
            const float z1o = p3 + fmaf(h1, w1h3, b13); \
            c1 = fsigmoid(z1f + 1.0f) * c1 + fsigmoid(z1i) * ftanh(z1j); \
            h1 = fsigmoid(z1o) * ftanh(c1); \
            const float ov = fmaf(h1, wd, bdv); \
            if (((s) & 63) == u) oval = ov; \
            if (((s) & 63) == 63) outrow[((s) & ~63) + u] = oval; \
        }

        for (int t = 0; t < TT; ++t) {
            __syncthreads();  // B(t+1)
            if (t > 0) L1STEP(t - 1)
        }
        __syncthreads();  // B(TT+1) -- makes ring slot (TT-1)&1 visible
        L1STEP(TT - 1)
        #undef L1STEP
    }
}

extern "C" void kernel_launch(void* const* d_in, const int* in_sizes, int n_in,
                              void* d_out, int out_size, void* d_ws, size_t ws_size,
                              hipStream_t stream) {
    const float* x  = (const float*)d_in[0];
    const float* W0 = (const float*)d_in[1];
    const float* b0 = (const float*)d_in[2];
    const float* W1 = (const float*)d_in[3];
    const float* b1 = (const float*)d_in[4];
    const float* Wd = (const float*)d_in[5];
    const float* bd = (const float*)d_in[6];
    float* out = (float*)d_out;
    lstm_ts_kernel<<<BB, NTHR, 0, stream>>>(x, W0, b0, W1, b1, Wd, bd, out);
}